// Round 13
// baseline (302.869 us; speedup 1.0000x reference)
//
#include <hip/hip_runtime.h>
#include <stdint.h>

#define HEADS 16
#define EMDIM 1024
#define DHEAD 64
#define BATCH 4
#define SEQQ 2048
#define SEQK 2048
#define NT (SEQK / 64)
// 0.125 * log2(e): folded into the Q projection so attn uses 2^x directly
#define QSCALE 0.18033688011112042f

typedef __attribute__((ext_vector_type(8))) short bf16x8;
typedef __attribute__((ext_vector_type(4))) float f32x4;
typedef __attribute__((ext_vector_type(4))) unsigned int u32x4;

typedef __attribute__((address_space(3))) void lds_void;
typedef const __attribute__((address_space(1))) void gbl_void;
#define GL_LDS16(g, l) __builtin_amdgcn_global_load_lds((gbl_void*)(g), (lds_void*)(l), 16, 0, 0)
#define MFMA16(a, b, c) __builtin_amdgcn_mfma_f32_16x16x32_bf16(a, b, c, 0, 0, 0)

__device__ __forceinline__ unsigned short f2bf(float f) {
    unsigned int u = __builtin_bit_cast(unsigned int, f);
    u += 0x7fffu + ((u >> 16) & 1u);
    return (unsigned short)(u >> 16);
}

__device__ __forceinline__ void exp2x4(float& a, float& b, float& c, float& d) {
    asm("v_exp_f32 %0, %0\n\t"
        "v_exp_f32 %1, %1\n\t"
        "v_exp_f32 %2, %2\n\t"
        "v_exp_f32 %3, %3\n\t"
        "s_nop 0"
        : "+v"(a), "+v"(b), "+v"(c), "+v"(d));
}

__device__ __forceinline__ unsigned int cvtpk_bf16(float lo, float hi) {
    unsigned int r;
    asm("v_cvt_pk_bf16_f32 %0, %1, %2" : "=v"(r) : "v"(lo), "v"(hi));
    return r;
}

// ---------------- prep: f32->bf16 conversion (5 tensors) ----------------
__global__ __launch_bounds__(256) void prep_all(const float* __restrict__ xq,
                                                const float* __restrict__ xkv,
                                                const float* __restrict__ wq,
                                                const float* __restrict__ wk,
                                                const float* __restrict__ wv,
                                                unsigned short* __restrict__ oxq,
                                                unsigned short* __restrict__ oxkv,
                                                unsigned short* __restrict__ owq,
                                                unsigned short* __restrict__ owk,
                                                unsigned short* __restrict__ owv) {
    const int NX = (BATCH * SEQQ * EMDIM) / 4;
    const int NW = (EMDIM * EMDIM) / 4;
    const int total = 2 * NX + 3 * NW;
    for (int i = blockIdx.x * 256 + threadIdx.x; i < total; i += gridDim.x * 256) {
        const float* src;
        unsigned short* dst;
        int j = i;
        if (j < NX) { src = xq; dst = oxq; }
        else if ((j -= NX) < NX) { src = xkv; dst = oxkv; }
        else if ((j -= NX) < NW) { src = wq; dst = owq; }
        else if ((j -= NW) < NW) { src = wk; dst = owk; }
        else { j -= NW; src = wv; dst = owv; }
        float4 v = reinterpret_cast<const float4*>(src)[j];
        ushort4 o;
        o.x = f2bf(v.x); o.y = f2bf(v.y); o.z = f2bf(v.z); o.w = f2bf(v.w);
        reinterpret_cast<ushort4*>(dst)[j] = o;
    }
}

// ---------------- fused QKV projection GEMM + overlapped mask bit-pack ----------------
// Blocks 0..1535: GEMM (XCD working-set remap, r12-green). Blocks 1536..1791: the
// r1/r5/r7-validated mask bit-pack (verbatim loop body; runs concurrent with GEMM,
// hiding its HBM traffic under the GEMM's latency-bound execution).
// nb 0..7 -> Q (pre-scaled by QSCALE), 8..15 -> K, 16..23 -> V^T
__global__ __launch_bounds__(256) void gemm_qkv(
    const unsigned short* __restrict__ xq, const unsigned short* __restrict__ xkv,
    const unsigned short* __restrict__ Wqm, const unsigned short* __restrict__ Wkm,
    const unsigned short* __restrict__ Wvm,
    const float* __restrict__ bq, const float* __restrict__ bk, const float* __restrict__ bv,
    unsigned short* __restrict__ Qo, unsigned short* __restrict__ Ko,
    unsigned short* __restrict__ Vo,
    const void* __restrict__ mask, unsigned long long* __restrict__ packed) {
    __shared__ __align__(16) unsigned short Alds[128 * 64];
    __shared__ __align__(16) unsigned short Blds[128 * 64];

    const int rawid = blockIdx.x;

    if (rawid >= 1536) {
        // ---- mask bit-pack (dtype-agnostic; bit kv = original index) ----
        const int bid = rawid - 1536;  // 0..255
        const int* mi = (const int*)mask;
        const uint8_t* mu = (const uint8_t*)mask;
        const int lane = threadIdx.x & 63;
        const bool u8src = __any(((unsigned)mi[lane]) > 1u);
        const size_t N = (size_t)BATCH * SEQQ * SEQK;
        const size_t stride = (size_t)256 * 256;
        for (size_t idx = (size_t)bid * 256 + threadIdx.x; idx < N; idx += stride) {
            const int v = u8src ? (int)mu[idx] : mi[idx];
            const unsigned long long bb = __ballot(v != 0);
            if (lane == 0) packed[idx >> 6] = bb;
        }
        return;
    }

    // ---- XCD remap: xcd = id&7 owns nb {3*xcd .. 3*xcd+2}; mt advances every 3 slots ----
    const int xcd = rawid & 7;
    const int slot = rawid >> 3;        // 0..191
    const int nb = xcd * 3 + slot % 3;  // 0..23
    const int mt = slot / 3;            // 0..63
    const int m0 = mt * 128;
    const int which = nb >> 3;  // 0=Q 1=K 2=V
    const unsigned short* A = (which == 0) ? xq : xkv;
    const unsigned short* W = (which == 0) ? Wqm : (which == 1) ? Wkm : Wvm;
    const float* bias = (which == 0) ? bq : (which == 1) ? bk : bv;
    const int n0 = (nb & 7) * 128;

    const int tid = threadIdx.x;
    const int lane = tid & 63;
    const int wid = tid >> 6;
    const int wm = wid >> 1, wn = wid & 1;
    const int lq = lane & 15, lh = lane >> 4;

    f32x4 acc[4][4] = {};

    const int srow = tid >> 3;
    const int scol = (tid & 7) * 8;

    for (int kt = 0; kt < 16; ++kt) {
        const int kb = kt * 64;
#pragma unroll
        for (int i = 0; i < 4; ++i) {
            const int row = i * 32 + srow;
            GL_LDS16(&A[(size_t)(m0 + row) * EMDIM + kb + scol], &Alds[row * 64 + scol]);
            GL_LDS16(&W[(size_t)(n0 + row) * EMDIM + kb + scol], &Blds[row * 64 + scol]);
        }
        __syncthreads();
#pragma unroll
        for (int ks = 0; ks < 2; ++ks) {
            bf16x8 af[4], bfr[4];
#pragma unroll
            for (int mf = 0; mf < 4; ++mf)
                af[mf] = *(const bf16x8*)&Alds[(wm * 64 + mf * 16 + lq) * 64 + ks * 32 + lh * 8];
#pragma unroll
            for (int nf = 0; nf < 4; ++nf)
                bfr[nf] = *(const bf16x8*)&Blds[(wn * 64 + nf * 16 + lq) * 64 + ks * 32 + lh * 8];
#pragma unroll
            for (int mf = 0; mf < 4; ++mf)
#pragma unroll
                for (int nf = 0; nf < 4; ++nf)
                    acc[mf][nf] = MFMA16(af[mf], bfr[nf], acc[mf][nf]);
        }
        __syncthreads();
    }

#pragma unroll
    for (int nf = 0; nf < 4; ++nf) {
        const int n = n0 + wn * 64 + nf * 16 + lq;
        const float bvv = bias[n];
        const int h = n >> 6, d = n & 63;
#pragma unroll
        for (int mf = 0; mf < 4; ++mf) {
            const int mbase = m0 + wm * 64 + mf * 16 + lh * 4;
            const int b = mbase >> 11;
            const int s = mbase & 2047;
            if (which == 2) {
                ushort4 pk;
                pk.x = f2bf(acc[mf][nf][0] + bvv);
                pk.y = f2bf(acc[mf][nf][1] + bvv);
                pk.z = f2bf(acc[mf][nf][2] + bvv);
                pk.w = f2bf(acc[mf][nf][3] + bvv);
                *(ushort4*)&Vo[(((size_t)(b * HEADS + h) * DHEAD) + d) * SEQK + s] = pk;
            } else {
                const float sc = (which == 0) ? QSCALE : 1.0f;
                unsigned short* o = (which == 0) ? Qo : Ko;
#pragma unroll
                for (int r = 0; r < 4; ++r) {
                    float v = (acc[mf][nf][r] + bvv) * sc;
                    o[(((size_t)(b * HEADS + h) * SEQQ) + (s + r)) * DHEAD + d] = f2bf(v);
                }
            }
        }
    }
}

// ---------------- fused flash attention (r7-green math; min-waves 4) ----------------
// Q (pre-scaled), K: [B*H, S, 64] bf16 ; VT: [B*H, 64, S] bf16 ; mpk: [B*SQ, NT] u64
// out: [B, SQ, HEADS*64] f32
// Grid (bh=64, qblk=16); 4 waves x 32 q-rows. LDS = K/V dbuf 32KB only.
// P in registers (permlane swaps). Mask pre-exp (-1e9 ternary). Denominator via ones-MFMA.
__global__ __launch_bounds__(256, 4) void attn_fused(const unsigned short* __restrict__ Q,
                                                     const unsigned short* __restrict__ K,
                                                     const unsigned short* __restrict__ VT,
                                                     const unsigned long long* __restrict__ mpk,
                                                     float* __restrict__ out) {
    const int tid = threadIdx.x;
    const int lane = tid & 63;
    const int wid = tid >> 6;
    const int lq = lane & 15, lh = lane >> 4;
    const int bh = blockIdx.x;  // same-bh blocks -> same XCD (id%8 == bh%8)
    const int b = bh >> 4, h = bh & 15;
    const int qbase = blockIdx.y * 128 + wid * 32;

    __shared__ __align__(16) unsigned short Kl[2][64 * 64];  // 16 KB
    __shared__ __align__(16) unsigned short Vl[2][64 * 64];  // 16 KB

    const unsigned short* Kbh = K + (size_t)bh * SEQK * DHEAD;
    const unsigned short* Vbh = VT + (size_t)bh * DHEAD * SEQK;

    bf16x8 bq[2][2];
    const unsigned long long* mrow[2];
#pragma unroll
    for (int sub = 0; sub < 2; ++sub) {
        const int q = qbase + sub * 16 + lq;
        const unsigned short* qrow = Q + ((size_t)bh * SEQQ + q) * DHEAD;
        bq[sub][0] = *(const bf16x8*)&qrow[lh * 8];
        bq[sub][1] = *(const bf16x8*)&qrow[32 + lh * 8];
        mrow[sub] = mpk + ((size_t)b * SEQQ + q) * NT;
    }

    f32x4 acc[4][2] = {};  // [vb][sub]
    f32x4 accl[2] = {};    // [sub] denominator via ones-MFMA

    const bf16x8 vone = {16256, 16256, 16256, 16256, 16256, 16256, 16256, 16256};  // bf16 1.0

    const int srow8 = lane >> 3;
    const int sg = (lane & 7) ^ srow8;   // pre-swizzled global source granule
    const int g7 = lq & 7;               // read-side granule XOR key (row&7)

    auto stage = [&](int s, int t) {
        const int k0 = t * 64;
#pragma unroll
        for (int i = 0; i < 2; ++i) {
            const int cc = wid * 2 + i;
            const int r = cc * 8 + srow8;
            GL_LDS16(Kbh + (size_t)(k0 + r) * DHEAD + sg * 8, &Kl[s][cc * 512]);
            GL_LDS16(Vbh + (size_t)r * SEQK + k0 + sg * 8, &Vl[s][cc * 512]);
        }
    };

    unsigned long long mwc[2], mwn[2];
#pragma unroll
    for (int sub = 0; sub < 2; ++sub) mwc[sub] = mrow[sub][0];

    stage(0, 0);
    __syncthreads();
    int cur = 0;

    for (int t = 0; t < NT; ++t) {
        if (t < NT - 1) {
            stage(cur ^ 1, t + 1);
#pragma unroll
            for (int sub = 0; sub < 2; ++sub) mwn[sub] = mrow[sub][t + 1];
        }

        // ---- S^T = K * Q^T -> masked 2^s -> packed bf16 pairs in registers ----
        uint2 w[2][4];  // [sub][kb]: .x = (r0,r1), .y = (r2,r3)
#pragma unroll
        for (int kb = 0; kb < 4; ++kb) {
            const unsigned short* kr = &Kl[cur][(kb * 16 + lq) * 64];
            const bf16x8 a0 = *(const bf16x8*)&kr[((0 + lh) ^ g7) * 8];
            const bf16x8 a1 = *(const bf16x8*)&kr[((4 + lh) ^ g7) * 8];
#pragma unroll
            for (int sub = 0; sub < 2; ++sub) {
                f32x4 z = {};
                z = MFMA16(a0, bq[sub][0], z);
                z = MFMA16(a1, bq[sub][1], z);
                const unsigned int ml = (unsigned int)(mwc[sub] >> (kb * 16 + lh * 4));
                float p0 = (ml & 1u) ? -1e9f : z[0];
                float p1 = (ml & 2u) ? -1e9f : z[1];
                float p2 = (ml & 4u) ? -1e9f : z[2];
                float p3 = (ml & 8u) ? -1e9f : z[3];
                exp2x4(p0, p1, p2, p3);
                w[sub][kb].x = cvtpk_bf16(p0, p1);
                w[sub][kb].y = cvtpk_bf16(p2, p3);
            }
        }

        // ---- in-register P^T -> B-fragment via permlane swaps (r5/r7-validated) ----
        bf16x8 pf[2][2];
#pragma unroll
        for (int sub = 0; sub < 2; ++sub) {
#pragma unroll
            for (int ks = 0; ks < 2; ++ks) {
                unsigned int s0 = w[sub][2 * ks].x, s2 = w[sub][2 * ks + 1].x;
                unsigned int s1 = w[sub][2 * ks].y, s3 = w[sub][2 * ks + 1].y;
                asm("v_permlane32_swap_b32 %0, %1" : "+v"(s0), "+v"(s2));
                asm("v_permlane32_swap_b32 %0, %1" : "+v"(s1), "+v"(s3));
                asm("v_permlane16_swap_b32 %0, %1" : "+v"(s0), "+v"(s2));
                asm("v_permlane16_swap_b32 %0, %1" : "+v"(s1), "+v"(s3));
                u32x4 fd = {s0, s1, s2, s3};
                pf[sub][ks] = __builtin_bit_cast(bf16x8, fd);
            }
        }

        // ---- PV: O^T += V^T * P^T ; l += ones * P^T (MFMA pipe) ----
        __builtin_amdgcn_s_setprio(1);
#pragma unroll
        for (int sub = 0; sub < 2; ++sub) {
            accl[sub] = MFMA16(vone, pf[sub][0], accl[sub]);
            accl[sub] = MFMA16(vone, pf[sub][1], accl[sub]);
        }
#pragma unroll
        for (int vb = 0; vb < 4; ++vb) {
            const unsigned short* vr = &Vl[cur][(vb * 16 + lq) * 64];
            const bf16x8 av0 = *(const bf16x8*)&vr[((0 + lh) ^ g7) * 8];
            const bf16x8 av1 = *(const bf16x8*)&vr[((4 + lh) ^ g7) * 8];
#pragma unroll
            for (int sub = 0; sub < 2; ++sub) {
                acc[vb][sub] = MFMA16(av0, pf[sub][0], acc[vb][sub]);
                acc[vb][sub] = MFMA16(av1, pf[sub][1], acc[vb][sub]);
            }
        }
        __builtin_amdgcn_s_setprio(0);

        __syncthreads();
        cur ^= 1;
#pragma unroll
        for (int sub = 0; sub < 2; ++sub) mwc[sub] = mwn[sub];
    }

    // ---- epilogue ----
#pragma unroll
    for (int sub = 0; sub < 2; ++sub) {
        const float rl = 1.f / accl[sub][0];
        const int q = qbase + sub * 16 + lq;
        float* orow = out + ((size_t)b * SEQQ + q) * (HEADS * DHEAD) + h * DHEAD;
#pragma unroll
        for (int vb = 0; vb < 4; ++vb) {
            float4 o4;
            o4.x = acc[vb][sub][0] * rl;
            o4.y = acc[vb][sub][1] * rl;
            o4.z = acc[vb][sub][2] * rl;
            o4.w = acc[vb][sub][3] * rl;
            *(float4*)&orow[vb * 16 + lh * 4] = o4;
        }
    }
}

// ---------------- launch ----------------
extern "C" void kernel_launch(void* const* d_in, const int* in_sizes, int n_in,
                              void* d_out, int out_size, void* d_ws, size_t ws_size,
                              hipStream_t stream) {
    const float* x_q  = (const float*)d_in[0];
    const float* x_kv = (const float*)d_in[1];
    const void*  mask = (const void*)d_in[2];
    const float* Wq_w = (const float*)d_in[3];
    const float* Wq_b = (const float*)d_in[4];
    const float* Wk_w = (const float*)d_in[5];
    const float* Wk_b = (const float*)d_in[6];
    const float* Wv_w = (const float*)d_in[7];
    const float* Wv_b = (const float*)d_in[8];
    float* out = (float*)d_out;

    char* ws = (char*)d_ws;
    const size_t SZ_QKV = (size_t)BATCH * HEADS * SEQQ * DHEAD * sizeof(unsigned short);  // 16 MB
    const size_t SZ_X   = (size_t)BATCH * SEQQ * EMDIM * sizeof(unsigned short);          // 16 MB
    const size_t SZ_W   = (size_t)EMDIM * EMDIM * sizeof(unsigned short);                 // 2 MB
    unsigned short* Qb  = (unsigned short*)(ws);
    unsigned short* Kb  = (unsigned short*)(ws + SZ_QKV);
    unsigned short* VTb = (unsigned short*)(ws + 2 * SZ_QKV);
    unsigned short* xqb = (unsigned short*)(ws + 3 * SZ_QKV);
    unsigned short* xkb = (unsigned short*)(ws + 3 * SZ_QKV + SZ_X);
    unsigned short* Wqb = (unsigned short*)(ws + 3 * SZ_QKV + 2 * SZ_X);
    unsigned short* Wkb = (unsigned short*)(ws + 3 * SZ_QKV + 2 * SZ_X + SZ_W);
    unsigned short* Wvb = (unsigned short*)(ws + 3 * SZ_QKV + 2 * SZ_X + 2 * SZ_W);
    unsigned long long* mpk = (unsigned long long*)(ws + 3 * SZ_QKV + 2 * SZ_X + 3 * SZ_W);

    prep_all<<<2048, 256, 0, stream>>>(x_q, x_kv, Wq_w, Wk_w, Wv_w, xqb, xkb, Wqb, Wkb, Wvb);

    gemm_qkv<<<1792, 256, 0, stream>>>(xqb, xkb, Wqb, Wkb, Wvb, Wq_b, Wk_b, Wv_b, Qb, Kb, VTb,
                                       mask, mpk);

    dim3 agrid(BATCH * HEADS, SEQQ / 128);  // 64 x 16
    attn_fused<<<agrid, 256, 0, stream>>>(Qb, Kb, VTb, mpk, out);
}

// Round 14
// 220.055 us; speedup vs baseline: 1.3763x; 1.3763x over previous
//
#include <hip/hip_runtime.h>
#include <stdint.h>

#define HEADS 16
#define EMDIM 1024
#define DHEAD 64
#define BATCH 4
#define SEQQ 2048
#define SEQK 2048
#define NT (SEQK / 64)
// 0.125 * log2(e): folded into the Q projection so attn uses 2^x directly
#define QSCALE 0.18033688011112042f

typedef __attribute__((ext_vector_type(8))) short bf16x8;
typedef __attribute__((ext_vector_type(4))) float f32x4;
typedef __attribute__((ext_vector_type(4))) unsigned int u32x4;

typedef __attribute__((address_space(3))) void lds_void;
typedef const __attribute__((address_space(1))) void gbl_void;
#define GL_LDS16(g, l) __builtin_amdgcn_global_load_lds((gbl_void*)(g), (lds_void*)(l), 16, 0, 0)
#define MFMA16(a, b, c) __builtin_amdgcn_mfma_f32_16x16x32_bf16(a, b, c, 0, 0, 0)

__device__ __forceinline__ unsigned short f2bf(float f) {
    unsigned int u = __builtin_bit_cast(unsigned int, f);
    u += 0x7fffu + ((u >> 16) & 1u);
    return (unsigned short)(u >> 16);
}

__device__ __forceinline__ void exp2x4(float& a, float& b, float& c, float& d) {
    asm("v_exp_f32 %0, %0\n\t"
        "v_exp_f32 %1, %1\n\t"
        "v_exp_f32 %2, %2\n\t"
        "v_exp_f32 %3, %3\n\t"
        "s_nop 0"
        : "+v"(a), "+v"(b), "+v"(c), "+v"(d));
}

__device__ __forceinline__ unsigned int cvtpk_bf16(float lo, float hi) {
    unsigned int r;
    asm("v_cvt_pk_bf16_f32 %0, %1, %2" : "=v"(r) : "v"(lo), "v"(hi));
    return r;
}

// ---------------- prep: f32->bf16 conversion (5 tensors) + mask bit-pack, one launch ----------------
__global__ __launch_bounds__(256) void prep_all(const float* __restrict__ xq,
                                                const float* __restrict__ xkv,
                                                const float* __restrict__ wq,
                                                const float* __restrict__ wk,
                                                const float* __restrict__ wv,
                                                unsigned short* __restrict__ oxq,
                                                unsigned short* __restrict__ oxkv,
                                                unsigned short* __restrict__ owq,
                                                unsigned short* __restrict__ owk,
                                                unsigned short* __restrict__ owv,
                                                const void* __restrict__ mask,
                                                unsigned long long* __restrict__ packed) {
    // --- phase 1: bf16 conversion ---
    const int NX = (BATCH * SEQQ * EMDIM) / 4;
    const int NW = (EMDIM * EMDIM) / 4;
    const int total = 2 * NX + 3 * NW;
    for (int i = blockIdx.x * 256 + threadIdx.x; i < total; i += gridDim.x * 256) {
        const float* src;
        unsigned short* dst;
        int j = i;
        if (j < NX) { src = xq; dst = oxq; }
        else if ((j -= NX) < NX) { src = xkv; dst = oxkv; }
        else if ((j -= NX) < NW) { src = wq; dst = owq; }
        else if ((j -= NW) < NW) { src = wk; dst = owk; }
        else { j -= NW; src = wv; dst = owv; }
        float4 v = reinterpret_cast<const float4*>(src)[j];
        ushort4 o;
        o.x = f2bf(v.x); o.y = f2bf(v.y); o.z = f2bf(v.z); o.w = f2bf(v.w);
        reinterpret_cast<ushort4*>(dst)[j] = o;
    }
    // --- phase 2: mask bit-pack (dtype-agnostic, r1/r5/r7-validated; bit kv = original index) ---
    const int* mi = (const int*)mask;
    const uint8_t* mu = (const uint8_t*)mask;
    const int lane = threadIdx.x & 63;
    const bool u8src = __any(((unsigned)mi[lane]) > 1u);
    const size_t N = (size_t)BATCH * SEQQ * SEQK;
    const size_t stride = (size_t)gridDim.x * blockDim.x;
    for (size_t idx = (size_t)blockIdx.x * blockDim.x + threadIdx.x; idx < N; idx += stride) {
        const int v = u8src ? (int)mu[idx] : mi[idx];
        const unsigned long long bb = __ballot(v != 0);
        if (lane == 0) packed[idx >> 6] = bb;
    }
}

// ---------------- fused QKV projection GEMM (m97 single-buffer, r12-green) ----------------
// XCD working-set remap: each XCD owns 3 fixed n-blocks (W L2-resident, 768 KB) and walks
// all m-tiles; 3 consecutive slots share one A-panel (L2-hot). Bijective over 1536 = 8*192.
// nb 0..7 -> Q (pre-scaled by QSCALE), 8..15 -> K, 16..23 -> V^T
__global__ __launch_bounds__(256) void gemm_qkv(
    const unsigned short* __restrict__ xq, const unsigned short* __restrict__ xkv,
    const unsigned short* __restrict__ Wqm, const unsigned short* __restrict__ Wkm,
    const unsigned short* __restrict__ Wvm,
    const float* __restrict__ bq, const float* __restrict__ bk, const float* __restrict__ bv,
    unsigned short* __restrict__ Qo, unsigned short* __restrict__ Ko,
    unsigned short* __restrict__ Vo) {
    __shared__ __align__(16) unsigned short Alds[128 * 64];
    __shared__ __align__(16) unsigned short Blds[128 * 64];

    // ---- XCD remap: xcd = id&7 owns nb {3*xcd .. 3*xcd+2}; mt advances every 3 slots ----
    const int rawid = blockIdx.y * gridDim.x + blockIdx.x;
    const int xcd = rawid & 7;
    const int slot = rawid >> 3;        // 0..191
    const int nb = xcd * 3 + slot % 3;  // 0..23
    const int mt = slot / 3;            // 0..63
    const int m0 = mt * 128;
    const int which = nb >> 3;  // 0=Q 1=K 2=V
    const unsigned short* A = (which == 0) ? xq : xkv;
    const unsigned short* W = (which == 0) ? Wqm : (which == 1) ? Wkm : Wvm;
    const float* bias = (which == 0) ? bq : (which == 1) ? bk : bv;
    const int n0 = (nb & 7) * 128;

    const int tid = threadIdx.x;
    const int lane = tid & 63;
    const int wid = tid >> 6;
    const int wm = wid >> 1, wn = wid & 1;
    const int lq = lane & 15, lh = lane >> 4;

    f32x4 acc[4][4] = {};

    const int srow = tid >> 3;
    const int scol = (tid & 7) * 8;

    for (int kt = 0; kt < 16; ++kt) {
        const int kb = kt * 64;
#pragma unroll
        for (int i = 0; i < 4; ++i) {
            const int row = i * 32 + srow;
            GL_LDS16(&A[(size_t)(m0 + row) * EMDIM + kb + scol], &Alds[row * 64 + scol]);
            GL_LDS16(&W[(size_t)(n0 + row) * EMDIM + kb + scol], &Blds[row * 64 + scol]);
        }
        __syncthreads();
#pragma unroll
        for (int ks = 0; ks < 2; ++ks) {
            bf16x8 af[4], bfr[4];
#pragma unroll
            for (int mf = 0; mf < 4; ++mf)
                af[mf] = *(const bf16x8*)&Alds[(wm * 64 + mf * 16 + lq) * 64 + ks * 32 + lh * 8];
#pragma unroll
            for (int nf = 0; nf < 4; ++nf)
                bfr[nf] = *(const bf16x8*)&Blds[(wn * 64 + nf * 16 + lq) * 64 + ks * 32 + lh * 8];
#pragma unroll
            for (int mf = 0; mf < 4; ++mf)
#pragma unroll
                for (int nf = 0; nf < 4; ++nf)
                    acc[mf][nf] = MFMA16(af[mf], bfr[nf], acc[mf][nf]);
        }
        __syncthreads();
    }

#pragma unroll
    for (int nf = 0; nf < 4; ++nf) {
        const int n = n0 + wn * 64 + nf * 16 + lq;
        const float bvv = bias[n];
        const int h = n >> 6, d = n & 63;
#pragma unroll
        for (int mf = 0; mf < 4; ++mf) {
            const int mbase = m0 + wm * 64 + mf * 16 + lh * 4;
            const int b = mbase >> 11;
            const int s = mbase & 2047;
            if (which == 2) {
                ushort4 pk;
                pk.x = f2bf(acc[mf][nf][0] + bvv);
                pk.y = f2bf(acc[mf][nf][1] + bvv);
                pk.z = f2bf(acc[mf][nf][2] + bvv);
                pk.w = f2bf(acc[mf][nf][3] + bvv);
                *(ushort4*)&Vo[(((size_t)(b * HEADS + h) * DHEAD) + d) * SEQK + s] = pk;
            } else {
                const float sc = (which == 0) ? QSCALE : 1.0f;
                unsigned short* o = (which == 0) ? Qo : Ko;
#pragma unroll
                for (int r = 0; r < 4; ++r) {
                    float v = (acc[mf][nf][r] + bvv) * sc;
                    o[(((size_t)(b * HEADS + h) * SEQQ) + (s + r)) * DHEAD + d] = f2bf(v);
                }
            }
        }
    }
}

// ---------------- fused flash attention (r7/r12-green math; min-waves 4) ----------------
// Q (pre-scaled), K: [B*H, S, 64] bf16 ; VT: [B*H, 64, S] bf16 ; mpk: [B*SQ, NT] u64
// out: [B, SQ, HEADS*64] f32
// Grid (bh=64, qblk=16); 4 waves x 32 q-rows. LDS = K/V dbuf 32KB -> 4 blocks/CU at LB(256,4).
// P in registers (permlane swaps). Mask pre-exp (-1e9 ternary). Denominator via ones-MFMA.
__global__ __launch_bounds__(256, 4) void attn_fused(const unsigned short* __restrict__ Q,
                                                     const unsigned short* __restrict__ K,
                                                     const unsigned short* __restrict__ VT,
                                                     const unsigned long long* __restrict__ mpk,
                                                     float* __restrict__ out) {
    const int tid = threadIdx.x;
    const int lane = tid & 63;
    const int wid = tid >> 6;
    const int lq = lane & 15, lh = lane >> 4;
    const int bh = blockIdx.x;  // same-bh blocks -> same XCD (id%8 == bh%8)
    const int b = bh >> 4, h = bh & 15;
    const int qbase = blockIdx.y * 128 + wid * 32;

    __shared__ __align__(16) unsigned short Kl[2][64 * 64];  // 16 KB
    __shared__ __align__(16) unsigned short Vl[2][64 * 64];  // 16 KB

    const unsigned short* Kbh = K + (size_t)bh * SEQK * DHEAD;
    const unsigned short* Vbh = VT + (size_t)bh * DHEAD * SEQK;

    bf16x8 bq[2][2];
    const unsigned long long* mrow[2];
#pragma unroll
    for (int sub = 0; sub < 2; ++sub) {
        const int q = qbase + sub * 16 + lq;
        const unsigned short* qrow = Q + ((size_t)bh * SEQQ + q) * DHEAD;
        bq[sub][0] = *(const bf16x8*)&qrow[lh * 8];
        bq[sub][1] = *(const bf16x8*)&qrow[32 + lh * 8];
        mrow[sub] = mpk + ((size_t)b * SEQQ + q) * NT;
    }

    f32x4 acc[4][2] = {};  // [vb][sub]
    f32x4 accl[2] = {};    // [sub] denominator via ones-MFMA

    const bf16x8 vone = {16256, 16256, 16256, 16256, 16256, 16256, 16256, 16256};  // bf16 1.0

    const int srow8 = lane >> 3;
    const int sg = (lane & 7) ^ srow8;   // pre-swizzled global source granule
    const int g7 = lq & 7;               // read-side granule XOR key (row&7)

    auto stage = [&](int s, int t) {
        const int k0 = t * 64;
#pragma unroll
        for (int i = 0; i < 2; ++i) {
            const int cc = wid * 2 + i;
            const int r = cc * 8 + srow8;
            GL_LDS16(Kbh + (size_t)(k0 + r) * DHEAD + sg * 8, &Kl[s][cc * 512]);
            GL_LDS16(Vbh + (size_t)r * SEQK + k0 + sg * 8, &Vl[s][cc * 512]);
        }
    };

    unsigned long long mwc[2], mwn[2];
#pragma unroll
    for (int sub = 0; sub < 2; ++sub) mwc[sub] = mrow[sub][0];

    stage(0, 0);
    __syncthreads();
    int cur = 0;

    for (int t = 0; t < NT; ++t) {
        if (t < NT - 1) {
            stage(cur ^ 1, t + 1);
#pragma unroll
            for (int sub = 0; sub < 2; ++sub) mwn[sub] = mrow[sub][t + 1];
        }

        // ---- S^T = K * Q^T -> masked 2^s -> packed bf16 pairs in registers ----
        uint2 w[2][4];  // [sub][kb]: .x = (r0,r1), .y = (r2,r3)
#pragma unroll
        for (int kb = 0; kb < 4; ++kb) {
            const unsigned short* kr = &Kl[cur][(kb * 16 + lq) * 64];
            const bf16x8 a0 = *(const bf16x8*)&kr[((0 + lh) ^ g7) * 8];
            const bf16x8 a1 = *(const bf16x8*)&kr[((4 + lh) ^ g7) * 8];
#pragma unroll
            for (int sub = 0; sub < 2; ++sub) {
                f32x4 z = {};
                z = MFMA16(a0, bq[sub][0], z);
                z = MFMA16(a1, bq[sub][1], z);
                const unsigned int ml = (unsigned int)(mwc[sub] >> (kb * 16 + lh * 4));
                float p0 = (ml & 1u) ? -1e9f : z[0];
                float p1 = (ml & 2u) ? -1e9f : z[1];
                float p2 = (ml & 4u) ? -1e9f : z[2];
                float p3 = (ml & 8u) ? -1e9f : z[3];
                exp2x4(p0, p1, p2, p3);
                w[sub][kb].x = cvtpk_bf16(p0, p1);
                w[sub][kb].y = cvtpk_bf16(p2, p3);
            }
        }

        // ---- in-register P^T -> B-fragment via permlane swaps (r5/r7-validated) ----
        bf16x8 pf[2][2];
#pragma unroll
        for (int sub = 0; sub < 2; ++sub) {
#pragma unroll
            for (int ks = 0; ks < 2; ++ks) {
                unsigned int s0 = w[sub][2 * ks].x, s2 = w[sub][2 * ks + 1].x;
                unsigned int s1 = w[sub][2 * ks].y, s3 = w[sub][2 * ks + 1].y;
                asm("v_permlane32_swap_b32 %0, %1" : "+v"(s0), "+v"(s2));
                asm("v_permlane32_swap_b32 %0, %1" : "+v"(s1), "+v"(s3));
                asm("v_permlane16_swap_b32 %0, %1" : "+v"(s0), "+v"(s2));
                asm("v_permlane16_swap_b32 %0, %1" : "+v"(s1), "+v"(s3));
                u32x4 fd = {s0, s1, s2, s3};
                pf[sub][ks] = __builtin_bit_cast(bf16x8, fd);
            }
        }

        // ---- PV: O^T += V^T * P^T ; l += ones * P^T (MFMA pipe) ----
        __builtin_amdgcn_s_setprio(1);
#pragma unroll
        for (int sub = 0; sub < 2; ++sub) {
            accl[sub] = MFMA16(vone, pf[sub][0], accl[sub]);
            accl[sub] = MFMA16(vone, pf[sub][1], accl[sub]);
        }
#pragma unroll
        for (int vb = 0; vb < 4; ++vb) {
            const unsigned short* vr = &Vl[cur][(vb * 16 + lq) * 64];
            const bf16x8 av0 = *(const bf16x8*)&vr[((0 + lh) ^ g7) * 8];
            const bf16x8 av1 = *(const bf16x8*)&vr[((4 + lh) ^ g7) * 8];
#pragma unroll
            for (int sub = 0; sub < 2; ++sub) {
                acc[vb][sub] = MFMA16(av0, pf[sub][0], acc[vb][sub]);
                acc[vb][sub] = MFMA16(av1, pf[sub][1], acc[vb][sub]);
            }
        }
        __builtin_amdgcn_s_setprio(0);

        __syncthreads();
        cur ^= 1;
#pragma unroll
        for (int sub = 0; sub < 2; ++sub) mwc[sub] = mwn[sub];
    }

    // ---- epilogue ----
#pragma unroll
    for (int sub = 0; sub < 2; ++sub) {
        const float rl = 1.f / accl[sub][0];
        const int q = qbase + sub * 16 + lq;
        float* orow = out + ((size_t)b * SEQQ + q) * (HEADS * DHEAD) + h * DHEAD;
#pragma unroll
        for (int vb = 0; vb < 4; ++vb) {
            float4 o4;
            o4.x = acc[vb][sub][0] * rl;
            o4.y = acc[vb][sub][1] * rl;
            o4.z = acc[vb][sub][2] * rl;
            o4.w = acc[vb][sub][3] * rl;
            *(float4*)&orow[vb * 16 + lh * 4] = o4;
        }
    }
}

// ---------------- launch ----------------
extern "C" void kernel_launch(void* const* d_in, const int* in_sizes, int n_in,
                              void* d_out, int out_size, void* d_ws, size_t ws_size,
                              hipStream_t stream) {
    const float* x_q  = (const float*)d_in[0];
    const float* x_kv = (const float*)d_in[1];
    const void*  mask = (const void*)d_in[2];
    const float* Wq_w = (const float*)d_in[3];
    const float* Wq_b = (const float*)d_in[4];
    const float* Wk_w = (const float*)d_in[5];
    const float* Wk_b = (const float*)d_in[6];
    const float* Wv_w = (const float*)d_in[7];
    const float* Wv_b = (const float*)d_in[8];
    float* out = (float*)d_out;

    char* ws = (char*)d_ws;
    const size_t SZ_QKV = (size_t)BATCH * HEADS * SEQQ * DHEAD * sizeof(unsigned short);  // 16 MB
    const size_t SZ_X   = (size_t)BATCH * SEQQ * EMDIM * sizeof(unsigned short);          // 16 MB
    const size_t SZ_W   = (size_t)EMDIM * EMDIM * sizeof(unsigned short);                 // 2 MB
    unsigned short* Qb  = (unsigned short*)(ws);
    unsigned short* Kb  = (unsigned short*)(ws + SZ_QKV);
    unsigned short* VTb = (unsigned short*)(ws + 2 * SZ_QKV);
    unsigned short* xqb = (unsigned short*)(ws + 3 * SZ_QKV);
    unsigned short* xkb = (unsigned short*)(ws + 3 * SZ_QKV + SZ_X);
    unsigned short* Wqb = (unsigned short*)(ws + 3 * SZ_QKV + 2 * SZ_X);
    unsigned short* Wkb = (unsigned short*)(ws + 3 * SZ_QKV + 2 * SZ_X + SZ_W);
    unsigned short* Wvb = (unsigned short*)(ws + 3 * SZ_QKV + 2 * SZ_X + 2 * SZ_W);
    unsigned long long* mpk = (unsigned long long*)(ws + 3 * SZ_QKV + 2 * SZ_X + 3 * SZ_W);

    prep_all<<<2048, 256, 0, stream>>>(x_q, x_kv, Wq_w, Wk_w, Wv_w, xqb, xkb, Wqb, Wkb, Wvb,
                                       mask, mpk);

    dim3 ggrid(24, BATCH * SEQQ / 128);  // 24 x 64 = 1536 blocks (remapped in-kernel)
    gemm_qkv<<<ggrid, 256, 0, stream>>>(xqb, xkb, Wqb, Wkb, Wvb, Wq_b, Wk_b, Wv_b, Qb, Kb, VTb);

    dim3 agrid(BATCH * HEADS, SEQQ / 128);  // 64 x 16
    attn_fused<<<agrid, 256, 0, stream>>>(Qb, Kb, VTb, mpk, out);
}

// Round 15
// 212.523 us; speedup vs baseline: 1.4251x; 1.0354x over previous
//
#include <hip/hip_runtime.h>
#include <stdint.h>

#define HEADS 16
#define EMDIM 1024
#define DHEAD 64
#define BATCH 4
#define SEQQ 2048
#define SEQK 2048
#define NT (SEQK / 64)
// 0.125 * log2(e): folded into the Q projection so attn uses 2^x directly
#define QSCALE 0.18033688011112042f

typedef __attribute__((ext_vector_type(8))) short bf16x8;
typedef __attribute__((ext_vector_type(4))) float f32x4;
typedef __attribute__((ext_vector_type(4))) unsigned int u32x4;

typedef __attribute__((address_space(3))) void lds_void;
typedef const __attribute__((address_space(1))) void gbl_void;
#define GL_LDS16(g, l) __builtin_amdgcn_global_load_lds((gbl_void*)(g), (lds_void*)(l), 16, 0, 0)
#define MFMA16(a, b, c) __builtin_amdgcn_mfma_f32_16x16x32_bf16(a, b, c, 0, 0, 0)

__device__ __forceinline__ unsigned short f2bf(float f) {
    unsigned int u = __builtin_bit_cast(unsigned int, f);
    u += 0x7fffu + ((u >> 16) & 1u);
    return (unsigned short)(u >> 16);
}

__device__ __forceinline__ void exp2x4(float& a, float& b, float& c, float& d) {
    asm("v_exp_f32 %0, %0\n\t"
        "v_exp_f32 %1, %1\n\t"
        "v_exp_f32 %2, %2\n\t"
        "v_exp_f32 %3, %3\n\t"
        "s_nop 0"
        : "+v"(a), "+v"(b), "+v"(c), "+v"(d));
}

__device__ __forceinline__ unsigned int cvtpk_bf16(float lo, float hi) {
    unsigned int r;
    asm("v_cvt_pk_bf16_f32 %0, %1, %2" : "=v"(r) : "v"(lo), "v"(hi));
    return r;
}

// ---------------- prep: f32->bf16 conversion (5 tensors) + mask bit-pack, one launch ----------------
__global__ __launch_bounds__(256) void prep_all(const float* __restrict__ xq,
                                                const float* __restrict__ xkv,
                                                const float* __restrict__ wq,
                                                const float* __restrict__ wk,
                                                const float* __restrict__ wv,
                                                unsigned short* __restrict__ oxq,
                                                unsigned short* __restrict__ oxkv,
                                                unsigned short* __restrict__ owq,
                                                unsigned short* __restrict__ owk,
                                                unsigned short* __restrict__ owv,
                                                const void* __restrict__ mask,
                                                unsigned long long* __restrict__ packed) {
    // --- phase 1: bf16 conversion ---
    const int NX = (BATCH * SEQQ * EMDIM) / 4;
    const int NW = (EMDIM * EMDIM) / 4;
    const int total = 2 * NX + 3 * NW;
    for (int i = blockIdx.x * 256 + threadIdx.x; i < total; i += gridDim.x * 256) {
        const float* src;
        unsigned short* dst;
        int j = i;
        if (j < NX) { src = xq; dst = oxq; }
        else if ((j -= NX) < NX) { src = xkv; dst = oxkv; }
        else if ((j -= NX) < NW) { src = wq; dst = owq; }
        else if ((j -= NW) < NW) { src = wk; dst = owk; }
        else { j -= NW; src = wv; dst = owv; }
        float4 v = reinterpret_cast<const float4*>(src)[j];
        ushort4 o;
        o.x = f2bf(v.x); o.y = f2bf(v.y); o.z = f2bf(v.z); o.w = f2bf(v.w);
        reinterpret_cast<ushort4*>(dst)[j] = o;
    }
    // --- phase 2: mask bit-pack (dtype-agnostic, r1/r5/r7-validated; bit kv = original index) ---
    const int* mi = (const int*)mask;
    const uint8_t* mu = (const uint8_t*)mask;
    const int lane = threadIdx.x & 63;
    const bool u8src = __any(((unsigned)mi[lane]) > 1u);
    const size_t N = (size_t)BATCH * SEQQ * SEQK;
    const size_t stride = (size_t)gridDim.x * blockDim.x;
    for (size_t idx = (size_t)blockIdx.x * blockDim.x + threadIdx.x; idx < N; idx += stride) {
        const int v = u8src ? (int)mu[idx] : mi[idx];
        const unsigned long long bb = __ballot(v != 0);
        if (lane == 0) packed[idx >> 6] = bb;
    }
}

// ---------------- fused QKV projection GEMM (counted-vmcnt double-buffer) ----------------
// XCD working-set remap (r12-green). Per K-step: stage(t+1) issued BEFORE compute(t);
// s_waitcnt vmcnt(8) keeps t+1's 8 global_load_lds in flight across the barrier and the
// MFMA phase (never drains to 0 in-loop). Hazards: stage->buf^1 guarded by previous
// iteration's lgkmcnt(0)+barrier; vmcnt(8) counts exactly the 8 just-issued GLs (no other
// in-loop VMEM); last tile drains vmcnt(0).
// nb 0..7 -> Q (pre-scaled by QSCALE), 8..15 -> K, 16..23 -> V^T
__global__ __launch_bounds__(256) void gemm_qkv(
    const unsigned short* __restrict__ xq, const unsigned short* __restrict__ xkv,
    const unsigned short* __restrict__ Wqm, const unsigned short* __restrict__ Wkm,
    const unsigned short* __restrict__ Wvm,
    const float* __restrict__ bq, const float* __restrict__ bk, const float* __restrict__ bv,
    unsigned short* __restrict__ Qo, unsigned short* __restrict__ Ko,
    unsigned short* __restrict__ Vo) {
    __shared__ __align__(16) unsigned short Alds[2][128 * 64];
    __shared__ __align__(16) unsigned short Blds[2][128 * 64];

    // ---- XCD remap: xcd = id&7 owns nb {3*xcd .. 3*xcd+2}; mt advances every 3 slots ----
    const int rawid = blockIdx.y * gridDim.x + blockIdx.x;
    const int xcd = rawid & 7;
    const int slot = rawid >> 3;        // 0..191
    const int nb = xcd * 3 + slot % 3;  // 0..23
    const int mt = slot / 3;            // 0..63
    const int m0 = mt * 128;
    const int which = nb >> 3;  // 0=Q 1=K 2=V
    const unsigned short* A = (which == 0) ? xq : xkv;
    const unsigned short* W = (which == 0) ? Wqm : (which == 1) ? Wkm : Wvm;
    const float* bias = (which == 0) ? bq : (which == 1) ? bk : bv;
    const int n0 = (nb & 7) * 128;

    const int tid = threadIdx.x;
    const int lane = tid & 63;
    const int wid = tid >> 6;
    const int wm = wid >> 1, wn = wid & 1;
    const int lq = lane & 15, lh = lane >> 4;

    f32x4 acc[4][4] = {};

    const int srow = tid >> 3;
    const int scol = (tid & 7) * 8;

    auto stage = [&](int s, int kt) {
        const int kb = kt * 64;
#pragma unroll
        for (int i = 0; i < 4; ++i) {
            const int row = i * 32 + srow;
            GL_LDS16(&A[(size_t)(m0 + row) * EMDIM + kb + scol], &Alds[s][row * 64 + scol]);
            GL_LDS16(&W[(size_t)(n0 + row) * EMDIM + kb + scol], &Blds[s][row * 64 + scol]);
        }
    };

    stage(0, 0);
    int cur = 0;
    for (int kt = 0; kt < 16; ++kt) {
        if (kt < 15) {
            stage(cur ^ 1, kt + 1);
            asm volatile("s_waitcnt vmcnt(8)" ::: "memory");  // tile kt landed; kt+1 in flight
        } else {
            asm volatile("s_waitcnt vmcnt(0)" ::: "memory");
        }
        __builtin_amdgcn_s_barrier();  // publish tile kt to all waves
#pragma unroll
        for (int ks = 0; ks < 2; ++ks) {
            bf16x8 af[4], bfr[4];
#pragma unroll
            for (int mf = 0; mf < 4; ++mf)
                af[mf] = *(const bf16x8*)&Alds[cur][(wm * 64 + mf * 16 + lq) * 64 + ks * 32 + lh * 8];
#pragma unroll
            for (int nf = 0; nf < 4; ++nf)
                bfr[nf] = *(const bf16x8*)&Blds[cur][(wn * 64 + nf * 16 + lq) * 64 + ks * 32 + lh * 8];
            __builtin_amdgcn_s_setprio(1);
#pragma unroll
            for (int mf = 0; mf < 4; ++mf)
#pragma unroll
                for (int nf = 0; nf < 4; ++nf)
                    acc[mf][nf] = MFMA16(af[mf], bfr[nf], acc[mf][nf]);
            __builtin_amdgcn_s_setprio(0);
        }
        asm volatile("s_waitcnt lgkmcnt(0)" ::: "memory");  // own ds_reads of buf[cur] done
        __builtin_amdgcn_s_barrier();                        // all waves done -> buf[cur] reusable
        cur ^= 1;
    }

#pragma unroll
    for (int nf = 0; nf < 4; ++nf) {
        const int n = n0 + wn * 64 + nf * 16 + lq;
        const float bvv = bias[n];
        const int h = n >> 6, d = n & 63;
#pragma unroll
        for (int mf = 0; mf < 4; ++mf) {
            const int mbase = m0 + wm * 64 + mf * 16 + lh * 4;
            const int b = mbase >> 11;
            const int s = mbase & 2047;
            if (which == 2) {
                ushort4 pk;
                pk.x = f2bf(acc[mf][nf][0] + bvv);
                pk.y = f2bf(acc[mf][nf][1] + bvv);
                pk.z = f2bf(acc[mf][nf][2] + bvv);
                pk.w = f2bf(acc[mf][nf][3] + bvv);
                *(ushort4*)&Vo[(((size_t)(b * HEADS + h) * DHEAD) + d) * SEQK + s] = pk;
            } else {
                const float sc = (which == 0) ? QSCALE : 1.0f;
                unsigned short* o = (which == 0) ? Qo : Ko;
#pragma unroll
                for (int r = 0; r < 4; ++r) {
                    float v = (acc[mf][nf][r] + bvv) * sc;
                    o[(((size_t)(b * HEADS + h) * SEQQ) + (s + r)) * DHEAD + d] = f2bf(v);
                }
            }
        }
    }
}

// ---------------- fused flash attention (r7/r12-green, verbatim) ----------------
// Q (pre-scaled), K: [B*H, S, 64] bf16 ; VT: [B*H, 64, S] bf16 ; mpk: [B*SQ, NT] u64
// out: [B, SQ, HEADS*64] f32
// Grid (bh=64, qblk=16); 4 waves x 32 q-rows. LDS = K/V dbuf 32KB only.
// P in registers (permlane swaps). Mask pre-exp (-1e9 ternary). Denominator via ones-MFMA.
__global__ __launch_bounds__(256, 3) void attn_fused(const unsigned short* __restrict__ Q,
                                                     const unsigned short* __restrict__ K,
                                                     const unsigned short* __restrict__ VT,
                                                     const unsigned long long* __restrict__ mpk,
                                                     float* __restrict__ out) {
    const int tid = threadIdx.x;
    const int lane = tid & 63;
    const int wid = tid >> 6;
    const int lq = lane & 15, lh = lane >> 4;
    const int bh = blockIdx.x;  // same-bh blocks -> same XCD (id%8 == bh%8)
    const int b = bh >> 4, h = bh & 15;
    const int qbase = blockIdx.y * 128 + wid * 32;

    __shared__ __align__(16) unsigned short Kl[2][64 * 64];  // 16 KB
    __shared__ __align__(16) unsigned short Vl[2][64 * 64];  // 16 KB

    const unsigned short* Kbh = K + (size_t)bh * SEQK * DHEAD;
    const unsigned short* Vbh = VT + (size_t)bh * DHEAD * SEQK;

    bf16x8 bq[2][2];
    const unsigned long long* mrow[2];
#pragma unroll
    for (int sub = 0; sub < 2; ++sub) {
        const int q = qbase + sub * 16 + lq;
        const unsigned short* qrow = Q + ((size_t)bh * SEQQ + q) * DHEAD;
        bq[sub][0] = *(const bf16x8*)&qrow[lh * 8];
        bq[sub][1] = *(const bf16x8*)&qrow[32 + lh * 8];
        mrow[sub] = mpk + ((size_t)b * SEQQ + q) * NT;
    }

    f32x4 acc[4][2] = {};  // [vb][sub]
    f32x4 accl[2] = {};    // [sub] denominator via ones-MFMA

    const bf16x8 vone = {16256, 16256, 16256, 16256, 16256, 16256, 16256, 16256};  // bf16 1.0

    const int srow8 = lane >> 3;
    const int sg = (lane & 7) ^ srow8;   // pre-swizzled global source granule
    const int g7 = lq & 7;               // read-side granule XOR key (row&7)

    auto stage = [&](int s, int t) {
        const int k0 = t * 64;
#pragma unroll
        for (int i = 0; i < 2; ++i) {
            const int cc = wid * 2 + i;
            const int r = cc * 8 + srow8;
            GL_LDS16(Kbh + (size_t)(k0 + r) * DHEAD + sg * 8, &Kl[s][cc * 512]);
            GL_LDS16(Vbh + (size_t)r * SEQK + k0 + sg * 8, &Vl[s][cc * 512]);
        }
    };

    unsigned long long mwc[2], mwn[2];
#pragma unroll
    for (int sub = 0; sub < 2; ++sub) mwc[sub] = mrow[sub][0];

    stage(0, 0);
    __syncthreads();
    int cur = 0;

    for (int t = 0; t < NT; ++t) {
        if (t < NT - 1) {
            stage(cur ^ 1, t + 1);
#pragma unroll
            for (int sub = 0; sub < 2; ++sub) mwn[sub] = mrow[sub][t + 1];
        }

        // ---- S^T = K * Q^T -> masked 2^s -> packed bf16 pairs in registers ----
        uint2 w[2][4];  // [sub][kb]: .x = (r0,r1), .y = (r2,r3)
#pragma unroll
        for (int kb = 0; kb < 4; ++kb) {
            const unsigned short* kr = &Kl[cur][(kb * 16 + lq) * 64];
            const bf16x8 a0 = *(const bf16x8*)&kr[((0 + lh) ^ g7) * 8];
            const bf16x8 a1 = *(const bf16x8*)&kr[((4 + lh) ^ g7) * 8];
#pragma unroll
            for (int sub = 0; sub < 2; ++sub) {
                f32x4 z = {};
                z = MFMA16(a0, bq[sub][0], z);
                z = MFMA16(a1, bq[sub][1], z);
                const unsigned int ml = (unsigned int)(mwc[sub] >> (kb * 16 + lh * 4));
                float p0 = (ml & 1u) ? -1e9f : z[0];
                float p1 = (ml & 2u) ? -1e9f : z[1];
                float p2 = (ml & 4u) ? -1e9f : z[2];
                float p3 = (ml & 8u) ? -1e9f : z[3];
                exp2x4(p0, p1, p2, p3);
                w[sub][kb].x = cvtpk_bf16(p0, p1);
                w[sub][kb].y = cvtpk_bf16(p2, p3);
            }
        }

        // ---- in-register P^T -> B-fragment via permlane swaps (r5/r7-validated) ----
        bf16x8 pf[2][2];
#pragma unroll
        for (int sub = 0; sub < 2; ++sub) {
#pragma unroll
            for (int ks = 0; ks < 2; ++ks) {
                unsigned int s0 = w[sub][2 * ks].x, s2 = w[sub][2 * ks + 1].x;
                unsigned int s1 = w[sub][2 * ks].y, s3 = w[sub][2 * ks + 1].y;
                asm("v_permlane32_swap_b32 %0, %1" : "+v"(s0), "+v"(s2));
                asm("v_permlane32_swap_b32 %0, %1" : "+v"(s1), "+v"(s3));
                asm("v_permlane16_swap_b32 %0, %1" : "+v"(s0), "+v"(s2));
                asm("v_permlane16_swap_b32 %0, %1" : "+v"(s1), "+v"(s3));
                u32x4 fd = {s0, s1, s2, s3};
                pf[sub][ks] = __builtin_bit_cast(bf16x8, fd);
            }
        }

        // ---- PV: O^T += V^T * P^T ; l += ones * P^T (MFMA pipe) ----
        __builtin_amdgcn_s_setprio(1);
#pragma unroll
        for (int sub = 0; sub < 2; ++sub) {
            accl[sub] = MFMA16(vone, pf[sub][0], accl[sub]);
            accl[sub] = MFMA16(vone, pf[sub][1], accl[sub]);
        }
#pragma unroll
        for (int vb = 0; vb < 4; ++vb) {
            const unsigned short* vr = &Vl[cur][(vb * 16 + lq) * 64];
            const bf16x8 av0 = *(const bf16x8*)&vr[((0 + lh) ^ g7) * 8];
            const bf16x8 av1 = *(const bf16x8*)&vr[((4 + lh) ^ g7) * 8];
#pragma unroll
            for (int sub = 0; sub < 2; ++sub) {
                acc[vb][sub] = MFMA16(av0, pf[sub][0], acc[vb][sub]);
                acc[vb][sub] = MFMA16(av1, pf[sub][1], acc[vb][sub]);
            }
        }
        __builtin_amdgcn_s_setprio(0);

        __syncthreads();
        cur ^= 1;
#pragma unroll
        for (int sub = 0; sub < 2; ++sub) mwc[sub] = mwn[sub];
    }

    // ---- epilogue ----
#pragma unroll
    for (int sub = 0; sub < 2; ++sub) {
        const float rl = 1.f / accl[sub][0];
        const int q = qbase + sub * 16 + lq;
        float* orow = out + ((size_t)b * SEQQ + q) * (HEADS * DHEAD) + h * DHEAD;
#pragma unroll
        for (int vb = 0; vb < 4; ++vb) {
            float4 o4;
            o4.x = acc[vb][sub][0] * rl;
            o4.y = acc[vb][sub][1] * rl;
            o4.z = acc[vb][sub][2] * rl;
            o4.w = acc[vb][sub][3] * rl;
            *(float4*)&orow[vb * 16 + lh * 4] = o4;
        }
    }
}

// ---------------- launch ----------------
extern "C" void kernel_launch(void* const* d_in, const int* in_sizes, int n_in,
                              void* d_out, int out_size, void* d_ws, size_t ws_size,
                              hipStream_t stream) {
    const float* x_q  = (const float*)d_in[0];
    const float* x_kv = (const float*)d_in[1];
    const void*  mask = (const void*)d_in[2];
    const float* Wq_w = (const float*)d_in[3];
    const float* Wq_b = (const float*)d_in[4];
    const float* Wk_w = (const float*)d_in[5];
    const float* Wk_b = (const float*)d_in[6];
    const float* Wv_w = (const float*)d_in[7];
    const float* Wv_b = (const float*)d_in[8];
    float* out = (float*)d_out;

    char* ws = (char*)d_ws;
    const size_t SZ_QKV = (size_t)BATCH * HEADS * SEQQ * DHEAD * sizeof(unsigned short);  // 16 MB
    const size_t SZ_X   = (size_t)BATCH * SEQQ * EMDIM * sizeof(unsigned short);          // 16 MB
    const size_t SZ_W   = (size_t)EMDIM * EMDIM * sizeof(unsigned short);                 // 2 MB
    unsigned short* Qb  = (unsigned short*)(ws);
    unsigned short* Kb  = (unsigned short*)(ws + SZ_QKV);
    unsigned short* VTb = (unsigned short*)(ws + 2 * SZ_QKV);
    unsigned short* xqb = (unsigned short*)(ws + 3 * SZ_QKV);
    unsigned short* xkb = (unsigned short*)(ws + 3 * SZ_QKV + SZ_X);
    unsigned short* Wqb = (unsigned short*)(ws + 3 * SZ_QKV + 2 * SZ_X);
    unsigned short* Wkb = (unsigned short*)(ws + 3 * SZ_QKV + 2 * SZ_X + SZ_W);
    unsigned short* Wvb = (unsigned short*)(ws + 3 * SZ_QKV + 2 * SZ_X + 2 * SZ_W);
    unsigned long long* mpk = (unsigned long long*)(ws + 3 * SZ_QKV + 2 * SZ_X + 3 * SZ_W);

    prep_all<<<2048, 256, 0, stream>>>(x_q, x_kv, Wq_w, Wk_w, Wv_w, xqb, xkb, Wqb, Wkb, Wvb,
                                       mask, mpk);

    dim3 ggrid(24, BATCH * SEQQ / 128);  // 24 x 64 = 1536 blocks (remapped in-kernel)
    gemm_qkv<<<ggrid, 256, 0, stream>>>(xqb, xkb, Wqb, Wkb, Wvb, Wq_b, Wk_b, Wv_b, Qb, Kb, VTb);

    dim3 agrid(BATCH * HEADS, SEQQ / 128);  // 64 x 16
    attn_fused<<<agrid, 256, 0, stream>>>(Qb, Kb, VTb, mpk, out);
}